// Round 4
// baseline (249.677 us; speedup 1.0000x reference)
//
#include <hip/hip_runtime.h>

#define GRID_W 512
#define GRID_H 512
#define HW (GRID_W * GRID_H)      // 262144
#define NPTS 250000
#define NB 2
#define NCELLS (NB * HW)          // 524288

// Voxel index matching XLA's lowering of (x - X0) / VOXEL:
// XLA algebraic simplifier rewrites divide-by-constant to multiply-by-
// reciprocal; 1/0.2f rounds to exactly 5.0f. So the reference computes
// trunc((x + 51.2f) * 5.0f). _rn intrinsics forbid contraction/rewrites.
__device__ __forceinline__ void cell_of(float x, float y, int& xi, int& yi) {
    xi = (int)__fmul_rn(__fadd_rn(x, 51.2f), 5.0f);
    yi = (int)__fmul_rn(__fadd_rn(y, 51.2f), 5.0f);
}

// -------------------- kernel 0: init winner array --------------------
__global__ __launch_bounds__(256) void k_init(int* __restrict__ win) {
    int i = blockIdx.x * 256 + threadIdx.x;
    if (i < NCELLS) win[i] = -1;
}

// -------------------- kernel 1: last-write-wins scatter --------------------
__global__ __launch_bounds__(256) void k_scatter(const float* __restrict__ pts,
                                                 int* __restrict__ win) {
    int gid = blockIdx.x * 256 + threadIdx.x;
    if (gid >= NB * NPTS) return;
    int b = gid / NPTS;
    int i = gid - b * NPTS;
    const float* p = pts + (size_t)gid * 5;
    int xi, yi;
    cell_of(p[0], p[1], xi, yi);
    if (xi >= 0 && xi < GRID_W && yi >= 0 && yi < GRID_H) {
        atomicMax(&win[b * HW + yi * GRID_W + xi], i);
    }
}

// -------------------- kernel 2: per-cell MLP + canvas write --------------------
__global__ __launch_bounds__(256) void k_mlp(
    const float* __restrict__ pts,
    const int* __restrict__ win,
    const float* __restrict__ W1, const float* __restrict__ b1,
    const float* __restrict__ g1, const float* __restrict__ be1,
    const float* __restrict__ m1, const float* __restrict__ v1,
    const float* __restrict__ W2, const float* __restrict__ b2,
    const float* __restrict__ g2, const float* __restrict__ be2,
    const float* __restrict__ m2, const float* __restrict__ v2,
    const float* __restrict__ W3, const float* __restrict__ b3,
    float* __restrict__ out)
{
    // folded weights in LDS (BN scale folded into W/bias)
    __shared__ float4 sW1[8][16];    //  2 KB
    __shared__ float4 sW2[64][16];   // 16 KB
    __shared__ float4 sW3[64][32];   // 32 KB
    __shared__ float4 sB1[16], sB2[16], sB3[32];
    __shared__ float  sS1[64], sS2[64];

    const int t = threadIdx.x;

    // ---- phase A: BN scale/bias fold + b3 copy ----
    if (t < 64) {
        float s1 = g1[t] / sqrtf(v1[t] + 1e-5f);
        sS1[t] = s1;
        ((float*)sB1)[t] = (b1[t] - m1[t]) * s1 + be1[t];
        float s2 = g2[t] / sqrtf(v2[t] + 1e-5f);
        sS2[t] = s2;
        ((float*)sB2)[t] = (b2[t] - m2[t]) * s2 + be2[t];
    } else if (t < 96) {
        sB3[t - 64] = ((const float4*)b3)[t - 64];
    }
    __syncthreads();

    // ---- phase B: fold weights into LDS ----
    if (t < 128) {                       // W1: 8x64 = 128 float4
        int r = t >> 4, c4 = t & 15;
        float4 w = ((const float4*)W1)[t];
        w.x *= sS1[c4 * 4 + 0];
        w.y *= sS1[c4 * 4 + 1];
        w.z *= sS1[c4 * 4 + 2];
        w.w *= sS1[c4 * 4 + 3];
        sW1[r][c4] = w;
    }
#pragma unroll
    for (int u = 0; u < 4; ++u) {        // W2: 64x64 = 1024 float4
        int e = t + u * 256;
        int r = e >> 4, c4 = e & 15;
        float4 w = ((const float4*)W2)[e];
        w.x *= sS2[c4 * 4 + 0];
        w.y *= sS2[c4 * 4 + 1];
        w.z *= sS2[c4 * 4 + 2];
        w.w *= sS2[c4 * 4 + 3];
        sW2[r][c4] = w;
    }
#pragma unroll
    for (int u = 0; u < 8; ++u) {        // W3: 64x128 = 2048 float4 (no fold)
        int e = t + u * 256;
        sW3[e >> 5][e & 31] = ((const float4*)W3)[e];
    }
    __syncthreads();

    // ---- per-cell work ----
    int gcell = blockIdx.x * 256 + t;            // 0 .. NCELLS-1
    int b = gcell >> 18;                         // / HW
    int cell = gcell & (HW - 1);
    int w = win[gcell];
    float* outp = out + (size_t)b * 128 * HW + cell;

    if (w < 0) {
#pragma unroll
        for (int c = 0; c < 128; ++c) outp[(size_t)c * HW] = 0.0f;
        return;
    }

    const float* p = pts + ((size_t)b * NPTS + w) * 5;
    float px = p[0], py = p[1], pz = p[2], pin = p[3], ptm = p[4];
    int xi, yi;
    cell_of(px, py, xi, yi);
    // centers: f32(xi)*0.2f + (-51.1f), separate roundings (no FMA), as XLA emits
    float xc = __fadd_rn(__fmul_rn((float)xi, 0.2f), -51.1f);
    float yc = __fadd_rn(__fmul_rn((float)yi, 0.2f), -51.1f);
    float a8[8] = {px, py, pz, pin, ptm,
                   __fadd_rn(px, -xc), __fadd_rn(py, -yc), 0.0f};

    // ---- layer 1: 8 -> 64 ----
    float h1[64];
#pragma unroll
    for (int j4 = 0; j4 < 16; ++j4) {
        float4 acc = sB1[j4];
#pragma unroll
        for (int i = 0; i < 8; ++i) {
            float4 wv = sW1[i][j4];
            acc.x += a8[i] * wv.x;
            acc.y += a8[i] * wv.y;
            acc.z += a8[i] * wv.z;
            acc.w += a8[i] * wv.w;
        }
        h1[j4 * 4 + 0] = fmaxf(acc.x, 0.0f);
        h1[j4 * 4 + 1] = fmaxf(acc.y, 0.0f);
        h1[j4 * 4 + 2] = fmaxf(acc.z, 0.0f);
        h1[j4 * 4 + 3] = fmaxf(acc.w, 0.0f);
    }

    // ---- layer 2: 64 -> 64 ----
    float h2[64];
#pragma unroll
    for (int j4 = 0; j4 < 16; ++j4) {
        float4 acc = sB2[j4];
#pragma unroll
        for (int k = 0; k < 64; ++k) {
            float4 wv = sW2[k][j4];
            float hv = h1[k];
            acc.x += hv * wv.x;
            acc.y += hv * wv.y;
            acc.z += hv * wv.z;
            acc.w += hv * wv.w;
        }
        h2[j4 * 4 + 0] = fmaxf(acc.x, 0.0f);
        h2[j4 * 4 + 1] = fmaxf(acc.y, 0.0f);
        h2[j4 * 4 + 2] = fmaxf(acc.z, 0.0f);
        h2[j4 * 4 + 3] = fmaxf(acc.w, 0.0f);
    }

    // ---- layer 3: 64 -> 128, in 4 blocks of 32 channels ----
    for (int cb = 0; cb < 4; ++cb) {
        float4 acc[8];
#pragma unroll
        for (int q = 0; q < 8; ++q) acc[q] = sB3[cb * 8 + q];
#pragma unroll
        for (int k = 0; k < 64; ++k) {
            float hv = h2[k];
#pragma unroll
            for (int q = 0; q < 8; ++q) {
                float4 wv = sW3[k][cb * 8 + q];
                acc[q].x += hv * wv.x;
                acc[q].y += hv * wv.y;
                acc[q].z += hv * wv.z;
                acc[q].w += hv * wv.w;
            }
        }
#pragma unroll
        for (int q = 0; q < 8; ++q) {
            int c = cb * 32 + q * 4;
            outp[(size_t)(c + 0) * HW] = acc[q].x;
            outp[(size_t)(c + 1) * HW] = acc[q].y;
            outp[(size_t)(c + 2) * HW] = acc[q].z;
            outp[(size_t)(c + 3) * HW] = acc[q].w;
        }
    }
}

extern "C" void kernel_launch(void* const* d_in, const int* in_sizes, int n_in,
                              void* d_out, int out_size, void* d_ws, size_t ws_size,
                              hipStream_t stream) {
    const float* pts = (const float*)d_in[0];
    const float* W1  = (const float*)d_in[1];
    const float* b1  = (const float*)d_in[2];
    const float* g1  = (const float*)d_in[3];
    const float* be1 = (const float*)d_in[4];
    const float* m1  = (const float*)d_in[5];
    const float* v1  = (const float*)d_in[6];
    const float* W2  = (const float*)d_in[7];
    const float* b2  = (const float*)d_in[8];
    const float* g2  = (const float*)d_in[9];
    const float* be2 = (const float*)d_in[10];
    const float* m2  = (const float*)d_in[11];
    const float* v2  = (const float*)d_in[12];
    const float* W3  = (const float*)d_in[13];
    const float* b3  = (const float*)d_in[14];
    float* out = (float*)d_out;
    int* win = (int*)d_ws;   // NCELLS ints = 2 MiB

    k_init<<<(NCELLS + 255) / 256, 256, 0, stream>>>(win);
    k_scatter<<<(NB * NPTS + 255) / 256, 256, 0, stream>>>(pts, win);
    k_mlp<<<NCELLS / 256, 256, 0, stream>>>(pts, win,
        W1, b1, g1, be1, m1, v1,
        W2, b2, g2, be2, m2, v2,
        W3, b3, out);
}